// Round 1
// baseline (842.770 us; speedup 1.0000x reference)
//
#include <hip/hip_runtime.h>
#include <math.h>

// Sizes fixed by the problem
static constexpr int Bn = 8, Ln = 1024, Dm = 512, Hn = 8, DhN = 64;

// ---------------- LayerNorm: one block per row of 512 ----------------
__global__ __launch_bounds__(256) void ln_kernel(const float* __restrict__ x,
                                                 const float* __restrict__ gamma,
                                                 const float* __restrict__ beta,
                                                 float* __restrict__ xn) {
  int row = blockIdx.x;
  int t = threadIdx.x;
  const float2 v = *(const float2*)(x + (size_t)row * Dm + t * 2);
  float s = v.x + v.y;
  float sq = v.x * v.x + v.y * v.y;
#pragma unroll
  for (int off = 32; off > 0; off >>= 1) {
    s += __shfl_down(s, off);
    sq += __shfl_down(sq, off);
  }
  __shared__ float red[8];
  int wave = t >> 6, lane = t & 63;
  if (lane == 0) { red[wave * 2] = s; red[wave * 2 + 1] = sq; }
  __syncthreads();
  float S = red[0] + red[2] + red[4] + red[6];
  float SQ = red[1] + red[3] + red[5] + red[7];
  float mu = S * (1.0f / Dm);
  float var = SQ * (1.0f / Dm) - mu * mu;
  float rstd = rsqrtf(var + 1e-5f);
  int c = t * 2;
  float2 o;
  o.x = (v.x - mu) * rstd * gamma[c] + beta[c];
  o.y = (v.y - mu) * rstd * gamma[c + 1] + beta[c + 1];
  *(float2*)(xn + (size_t)row * Dm + c) = o;
}

// ---------------- Sinusoidal relative-position table pe[l][k], 1024x512 ----------------
__global__ __launch_bounds__(256) void pe_kernel(float* __restrict__ pe) {
  int idx = blockIdx.x * 256 + threadIdx.x;  // < 1024*512
  int l = idx >> 9, k = idx & 511;
  // freqs[k] = exp(-2k * ln(10000)/512)
  float freq = expf(-0.0359778921f * (float)k);
  float angle = (float)(l - k) * freq;
  pe[idx] = (k & 1) ? sinf(angle) : cosf(angle);
}

// ---------------- Generic NT GEMM: C[m][n] = sum_k A[m][k]*Bw[n][k] (+bias[n]) ----------------
// mode 0: scatter qkv -> out + part*4194304, layout (B,H,L,Dh)
// mode 1: scatter pos -> layout (H,L,Dh)
// mode 2: plain row-major out[m*N+n]
__global__ __launch_bounds__(256) void gemm_nt(const float* __restrict__ A,
                                               const float* __restrict__ Bw,
                                               const float* __restrict__ bias,
                                               float* __restrict__ out,
                                               int M, int N, int K, int mode) {
  __shared__ float As[64][37];  // +5 pad: keeps inner-loop bank aliasing <=2-way
  __shared__ float Bs[64][37];
  const int tx = threadIdx.x, ty = threadIdx.y;
  const int t = ty * 16 + tx;
  const int m0 = blockIdx.y * 64, n0 = blockIdx.x * 64;
  float acc[4][4] = {};
  for (int k0 = 0; k0 < K; k0 += 32) {
    __syncthreads();
#pragma unroll
    for (int s = 0; s < 2; ++s) {
      int idx = t + s * 256;       // 0..511
      int row = idx >> 3;
      int c4 = (idx & 7) << 2;
      float4 av = *(const float4*)(A + (size_t)(m0 + row) * K + k0 + c4);
      As[row][c4] = av.x; As[row][c4 + 1] = av.y;
      As[row][c4 + 2] = av.z; As[row][c4 + 3] = av.w;
      float4 bv = *(const float4*)(Bw + (size_t)(n0 + row) * K + k0 + c4);
      Bs[row][c4] = bv.x; Bs[row][c4 + 1] = bv.y;
      Bs[row][c4 + 2] = bv.z; Bs[row][c4 + 3] = bv.w;
    }
    __syncthreads();
#pragma unroll
    for (int kk = 0; kk < 32; ++kk) {
      float a[4], b[4];
#pragma unroll
      for (int i = 0; i < 4; ++i) a[i] = As[ty * 4 + i][kk];
#pragma unroll
      for (int j = 0; j < 4; ++j) b[j] = Bs[tx * 4 + j][kk];
#pragma unroll
      for (int i = 0; i < 4; ++i)
#pragma unroll
        for (int j = 0; j < 4; ++j) acc[i][j] += a[i] * b[j];
    }
  }
#pragma unroll
  for (int i = 0; i < 4; ++i) {
    int m = m0 + ty * 4 + i;
#pragma unroll
    for (int j = 0; j < 4; ++j) {
      int n = n0 + tx * 4 + j;
      float val = acc[i][j] + (bias ? bias[n] : 0.0f);
      if (mode == 0) {
        int part = n >> 9, h = (n >> 6) & 7, dh = n & 63;
        int bb = m >> 10, l = m & 1023;
        out[(size_t)part * 4194304 + (size_t)((bb * 8 + h) * 1024 + l) * 64 + dh] = val;
      } else if (mode == 1) {
        int h = n >> 6, dh = n & 63;
        out[(size_t)(h * 1024 + m) * 64 + dh] = val;
      } else {
        out[(size_t)m * N + n] = val;
      }
    }
  }
}

// ---------------- Fold: K' = k + pos[h]; bias[g] = u_h.k + vb_h.pos (one wave per key row) ----------------
__global__ __launch_bounds__(256) void fold_kernel(float* __restrict__ kbuf,
                                                   const float* __restrict__ pos,
                                                   const float* __restrict__ ub,
                                                   const float* __restrict__ vbb,
                                                   float* __restrict__ biasout) {
  int t = threadIdx.x;
  int wave = t >> 6, lane = t & 63;
  int g = blockIdx.x * 4 + wave;  // [0, B*H*L)
  int h = (g >> 10) & 7;
  int m = g & 1023;
  float kv = kbuf[(size_t)g * 64 + lane];
  float pv = pos[(size_t)(h * 1024 + m) * 64 + lane];
  float val = ub[h * 64 + lane] * kv + vbb[h * 64 + lane] * pv;
#pragma unroll
  for (int off = 32; off > 0; off >>= 1) val += __shfl_down(val, off);
  if (lane == 0) biasout[g] = val;
  kbuf[(size_t)g * 64 + lane] = kv + pv;
}

// ---------------- Flash attention with per-key additive bias ----------------
// grid: (L/64, B*H); block 16x16. S[l,m] = 0.125*(q_l . K'_m + bias_m)
__global__ __launch_bounds__(256) void flash_kernel(const float* __restrict__ q,
                                                    const float* __restrict__ kp,
                                                    const float* __restrict__ v,
                                                    const float* __restrict__ bias,
                                                    float* __restrict__ attn_out) {
  __shared__ float Qs[64][65];
  __shared__ float KPs[64][65];  // K' tile, later overlaid with P tile
  __shared__ float Vs[64][64];
  __shared__ float Bb[64];
  const int tx = threadIdx.x, ty = threadIdx.y;
  const int t = ty * 16 + tx;
  const int bh = blockIdx.y, qt = blockIdx.x;
  const float* qb = q + (size_t)bh * (Ln * DhN);
  const float* kb = kp + (size_t)bh * (Ln * DhN);
  const float* vb = v + (size_t)bh * (Ln * DhN);
  const float* bb = bias + (size_t)bh * Ln;
#pragma unroll
  for (int s = 0; s < 4; ++s) {
    int idx = t + s * 256;  // < 1024 float4s
    int r = idx >> 4, c4 = (idx & 15) << 2;
    float4 av = *(const float4*)(qb + (size_t)(qt * 64 + r) * 64 + c4);
    Qs[r][c4] = av.x; Qs[r][c4 + 1] = av.y; Qs[r][c4 + 2] = av.z; Qs[r][c4 + 3] = av.w;
  }
  float m_st[4], l_st[4], o[4][4] = {};
#pragma unroll
  for (int i = 0; i < 4; ++i) { m_st[i] = -INFINITY; l_st[i] = 0.0f; }

  for (int kt = 0; kt < 16; ++kt) {
    __syncthreads();  // previous P@V done before overwriting KPs/Vs
#pragma unroll
    for (int s = 0; s < 4; ++s) {
      int idx = t + s * 256;
      int r = idx >> 4, c4 = (idx & 15) << 2;
      float4 av = *(const float4*)(kb + (size_t)(kt * 64 + r) * 64 + c4);
      KPs[r][c4] = av.x; KPs[r][c4 + 1] = av.y; KPs[r][c4 + 2] = av.z; KPs[r][c4 + 3] = av.w;
      float4 vv = *(const float4*)(vb + (size_t)(kt * 64 + r) * 64 + c4);
      *(float4*)&Vs[r][c4] = vv;
    }
    if (t < 64) Bb[t] = bb[kt * 64 + t];
    __syncthreads();
    // scores
    float sc[4][4] = {};
#pragma unroll
    for (int kk = 0; kk < 64; ++kk) {
      float qa[4], ka[4];
#pragma unroll
      for (int i = 0; i < 4; ++i) qa[i] = Qs[ty * 4 + i][kk];
#pragma unroll
      for (int j = 0; j < 4; ++j) ka[j] = KPs[tx * 4 + j][kk];
#pragma unroll
      for (int i = 0; i < 4; ++i)
#pragma unroll
        for (int j = 0; j < 4; ++j) sc[i][j] += qa[i] * ka[j];
    }
    // online softmax (reductions across the 16 tx lanes of each row group)
    float alpha[4];
#pragma unroll
    for (int i = 0; i < 4; ++i) {
#pragma unroll
      for (int j = 0; j < 4; ++j) sc[i][j] = (sc[i][j] + Bb[tx * 4 + j]) * 0.125f;
      float rm = fmaxf(fmaxf(sc[i][0], sc[i][1]), fmaxf(sc[i][2], sc[i][3]));
#pragma unroll
      for (int msk = 1; msk < 16; msk <<= 1) rm = fmaxf(rm, __shfl_xor(rm, msk));
      float mn = fmaxf(m_st[i], rm);
      alpha[i] = expf(m_st[i] - mn);
      m_st[i] = mn;
      float su = 0.0f;
#pragma unroll
      for (int j = 0; j < 4; ++j) { sc[i][j] = expf(sc[i][j] - mn); su += sc[i][j]; }
#pragma unroll
      for (int msk = 1; msk < 16; msk <<= 1) su += __shfl_xor(su, msk);
      l_st[i] = l_st[i] * alpha[i] + su;
#pragma unroll
      for (int j = 0; j < 4; ++j) o[i][j] *= alpha[i];
    }
    __syncthreads();  // all K'-reads done before P overlays KPs
#pragma unroll
    for (int i = 0; i < 4; ++i)
#pragma unroll
      for (int j = 0; j < 4; ++j) KPs[ty * 4 + i][tx * 4 + j] = sc[i][j];
    __syncthreads();
    // O += P @ V
#pragma unroll
    for (int kk = 0; kk < 64; ++kk) {
      float pa[4], va[4];
#pragma unroll
      for (int i = 0; i < 4; ++i) pa[i] = KPs[ty * 4 + i][kk];
#pragma unroll
      for (int j = 0; j < 4; ++j) va[j] = Vs[kk][tx * 4 + j];
#pragma unroll
      for (int i = 0; i < 4; ++i)
#pragma unroll
        for (int j = 0; j < 4; ++j) o[i][j] += pa[i] * va[j];
    }
  }
  const int bidx = bh >> 3, h = bh & 7;
#pragma unroll
  for (int i = 0; i < 4; ++i) {
    int l = qt * 64 + ty * 4 + i;
    float inv = 1.0f / l_st[i];
#pragma unroll
    for (int j = 0; j < 4; ++j) {
      attn_out[(size_t)(bidx * 1024 + l) * 512 + h * 64 + tx * 4 + j] = o[i][j] * inv;
    }
  }
}

extern "C" void kernel_launch(void* const* d_in, const int* in_sizes, int n_in,
                              void* d_out, int out_size, void* d_ws, size_t ws_size,
                              hipStream_t stream) {
  const float* x      = (const float*)d_in[0];
  const float* gamma  = (const float*)d_in[1];
  const float* beta   = (const float*)d_in[2];
  const float* w_qkv  = (const float*)d_in[3];
  const float* b_qkv  = (const float*)d_in[4];
  const float* w_pos  = (const float*)d_in[5];
  const float* w_out  = (const float*)d_in[6];
  const float* b_out  = (const float*)d_in[7];
  const float* u_bias = (const float*)d_in[8];
  const float* v_bias = (const float*)d_in[9];
  float* out = (float*)d_out;
  float* ws = (float*)d_ws;

  // ws layout (floats). region0 is time-shared: xn -> pe -> attn_out.
  float* region0 = ws;                 // 4,194,304
  float* qb    = ws + 4194304;         // 4,194,304 (B,H,L,Dh)
  float* kb    = ws + 8388608;         // 4,194,304 -> becomes K' in place
  float* vbuf  = ws + 12582912;        // 4,194,304
  float* posb  = ws + 16777216;        //   524,288 (H,L,Dh)
  float* biasb = ws + 17301504;        //    65,536 (B,H,L)
  // total ~69.5 MB

  ln_kernel<<<8192, 256, 0, stream>>>(x, gamma, beta, region0);
  gemm_nt<<<dim3(24, 128), dim3(16, 16), 0, stream>>>(region0, w_qkv, b_qkv, qb,
                                                      8192, 1536, 512, 0);
  pe_kernel<<<2048, 256, 0, stream>>>(region0);
  gemm_nt<<<dim3(8, 16), dim3(16, 16), 0, stream>>>(region0, w_pos, nullptr, posb,
                                                    1024, 512, 512, 1);
  fold_kernel<<<16384, 256, 0, stream>>>(kb, posb, u_bias, v_bias, biasb);
  flash_kernel<<<dim3(16, 64), dim3(16, 16), 0, stream>>>(qb, kb, vbuf, biasb, region0);
  gemm_nt<<<dim3(8, 128), dim3(16, 16), 0, stream>>>(region0, w_out, b_out, out,
                                                     8192, 512, 512, 2);
}

// Round 2
// 552.269 us; speedup vs baseline: 1.5260x; 1.5260x over previous
//
#include <hip/hip_runtime.h>
#include <math.h>

static constexpr int Bn = 8, Ln = 1024, Dm = 512, Hn = 8, DhN = 64;

typedef short bf16x8 __attribute__((ext_vector_type(8)));
typedef float f32x4 __attribute__((ext_vector_type(4)));

static __device__ __forceinline__ unsigned short f2b(float f) {
  union { float f; unsigned int u; } x;
  x.f = f;
  unsigned int u = x.u;
  unsigned int r = (u + 0x7FFFu + ((u >> 16) & 1u)) >> 16;  // RNE
  return (unsigned short)r;
}

// ---------------- LayerNorm ----------------
__global__ __launch_bounds__(256) void ln_kernel(const float* __restrict__ x,
                                                 const float* __restrict__ gamma,
                                                 const float* __restrict__ beta,
                                                 float* __restrict__ xn) {
  int row = blockIdx.x;
  int t = threadIdx.x;
  const float2 v = *(const float2*)(x + (size_t)row * Dm + t * 2);
  float s = v.x + v.y;
  float sq = v.x * v.x + v.y * v.y;
#pragma unroll
  for (int off = 32; off > 0; off >>= 1) {
    s += __shfl_down(s, off);
    sq += __shfl_down(sq, off);
  }
  __shared__ float red[8];
  int wave = t >> 6, lane = t & 63;
  if (lane == 0) { red[wave * 2] = s; red[wave * 2 + 1] = sq; }
  __syncthreads();
  float S = red[0] + red[2] + red[4] + red[6];
  float SQ = red[1] + red[3] + red[5] + red[7];
  float mu = S * (1.0f / Dm);
  float var = SQ * (1.0f / Dm) - mu * mu;
  float rstd = rsqrtf(var + 1e-5f);
  int c = t * 2;
  float2 o;
  o.x = (v.x - mu) * rstd * gamma[c] + beta[c];
  o.y = (v.y - mu) * rstd * gamma[c + 1] + beta[c + 1];
  *(float2*)(xn + (size_t)row * Dm + c) = o;
}

// ---------------- Sinusoidal pe[l][k] ----------------
__global__ __launch_bounds__(256) void pe_kernel(float* __restrict__ pe) {
  int idx = blockIdx.x * 256 + threadIdx.x;
  int l = idx >> 9, k = idx & 511;
  float freq = expf(-0.0359778921f * (float)k);
  float angle = (float)(l - k) * freq;
  pe[idx] = (k & 1) ? sinf(angle) : cosf(angle);
}

// ---------------- f32 NT GEMM (unchanged this round) ----------------
__global__ __launch_bounds__(256) void gemm_nt(const float* __restrict__ A,
                                               const float* __restrict__ Bw,
                                               const float* __restrict__ bias,
                                               float* __restrict__ out,
                                               int M, int N, int K, int mode) {
  __shared__ float As[64][37];
  __shared__ float Bs[64][37];
  const int tx = threadIdx.x, ty = threadIdx.y;
  const int t = ty * 16 + tx;
  const int m0 = blockIdx.y * 64, n0 = blockIdx.x * 64;
  float acc[4][4] = {};
  for (int k0 = 0; k0 < K; k0 += 32) {
    __syncthreads();
#pragma unroll
    for (int s = 0; s < 2; ++s) {
      int idx = t + s * 256;
      int row = idx >> 3;
      int c4 = (idx & 7) << 2;
      float4 av = *(const float4*)(A + (size_t)(m0 + row) * K + k0 + c4);
      As[row][c4] = av.x; As[row][c4 + 1] = av.y;
      As[row][c4 + 2] = av.z; As[row][c4 + 3] = av.w;
      float4 bv = *(const float4*)(Bw + (size_t)(n0 + row) * K + k0 + c4);
      Bs[row][c4] = bv.x; Bs[row][c4 + 1] = bv.y;
      Bs[row][c4 + 2] = bv.z; Bs[row][c4 + 3] = bv.w;
    }
    __syncthreads();
#pragma unroll
    for (int kk = 0; kk < 32; ++kk) {
      float a[4], b[4];
#pragma unroll
      for (int i = 0; i < 4; ++i) a[i] = As[ty * 4 + i][kk];
#pragma unroll
      for (int j = 0; j < 4; ++j) b[j] = Bs[tx * 4 + j][kk];
#pragma unroll
      for (int i = 0; i < 4; ++i)
#pragma unroll
        for (int j = 0; j < 4; ++j) acc[i][j] += a[i] * b[j];
    }
  }
#pragma unroll
  for (int i = 0; i < 4; ++i) {
    int m = m0 + ty * 4 + i;
#pragma unroll
    for (int j = 0; j < 4; ++j) {
      int n = n0 + tx * 4 + j;
      float val = acc[i][j] + (bias ? bias[n] : 0.0f);
      if (mode == 0) {
        int part = n >> 9, h = (n >> 6) & 7, dh = n & 63;
        int bb = m >> 10, l = m & 1023;
        out[(size_t)part * 4194304 + (size_t)((bb * 8 + h) * 1024 + l) * 64 + dh] = val;
      } else if (mode == 1) {
        int h = n >> 6, dh = n & 63;
        out[(size_t)(h * 1024 + m) * 64 + dh] = val;
      } else {
        out[(size_t)m * N + n] = val;
      }
    }
  }
}

// ---------------- Fold: K' = k + pos[h] (bf16 out); bias = u.k + vb.pos ----------------
__global__ __launch_bounds__(256) void fold_kernel(const float* __restrict__ kbuf,
                                                   const float* __restrict__ pos,
                                                   const float* __restrict__ ub,
                                                   const float* __restrict__ vbb,
                                                   float* __restrict__ biasout,
                                                   unsigned short* __restrict__ kbf) {
  int t = threadIdx.x;
  int wave = t >> 6, lane = t & 63;
  int g = blockIdx.x * 4 + wave;  // [0, B*H*L)
  int h = (g >> 10) & 7;
  int m = g & 1023;
  float kv = kbuf[(size_t)g * 64 + lane];
  float pv = pos[(size_t)(h * 1024 + m) * 64 + lane];
  float val = ub[h * 64 + lane] * kv + vbb[h * 64 + lane] * pv;
#pragma unroll
  for (int off = 32; off > 0; off >>= 1) val += __shfl_down(val, off);
  if (lane == 0) biasout[g] = val;
  kbf[(size_t)g * 64 + lane] = f2b(kv + pv);
}

// ---------------- Q f32 -> bf16 ----------------
__global__ __launch_bounds__(256) void convq_kernel(const float* __restrict__ q,
                                                    unsigned short* __restrict__ qb) {
  int i = blockIdx.x * 256 + threadIdx.x;
  float4 v = *(const float4*)(q + (size_t)i * 4);
  ushort4 o;
  o.x = f2b(v.x); o.y = f2b(v.y); o.z = f2b(v.z); o.w = f2b(v.w);
  *(ushort4*)(qb + (size_t)i * 4) = o;
}

// ---------------- V (b,h,l,d) f32 -> Vt (b,h,d,l) bf16 ----------------
__global__ __launch_bounds__(256) void transv_kernel(const float* __restrict__ v,
                                                     unsigned short* __restrict__ vt) {
  __shared__ float Ts[64 * 65];
  int t = threadIdx.x;
  int bh = blockIdx.y, lt = blockIdx.x;
  const float* vg = v + (size_t)bh * 65536 + lt * 64 * 64;
#pragma unroll
  for (int s = 0; s < 4; ++s) {
    int idx = t + s * 256;
    int r = idx >> 4, c4 = (idx & 15) << 2;
    float4 ld = *(const float4*)(vg + r * 64 + c4);
    Ts[r * 65 + c4] = ld.x; Ts[r * 65 + c4 + 1] = ld.y;
    Ts[r * 65 + c4 + 2] = ld.z; Ts[r * 65 + c4 + 3] = ld.w;
  }
  __syncthreads();
#pragma unroll
  for (int s = 0; s < 4; ++s) {
    int idx = t + s * 256;
    int d = idx >> 4, l4 = (idx & 15) << 2;
    ushort4 o;
    o.x = f2b(Ts[(l4 + 0) * 65 + d]);
    o.y = f2b(Ts[(l4 + 1) * 65 + d]);
    o.z = f2b(Ts[(l4 + 2) * 65 + d]);
    o.w = f2b(Ts[(l4 + 3) * 65 + d]);
    *(ushort4*)(vt + (size_t)bh * 65536 + d * 1024 + lt * 64 + l4) = o;
  }
}

// ---------------- Flash attention, bf16 MFMA 16x16x32 ----------------
// grid (16, 64), 256 threads = 4 waves; wave w owns Q rows [w*16, w*16+16).
__global__ __launch_bounds__(256) void flash_mfma(const unsigned short* __restrict__ qbf,
                                                  const unsigned short* __restrict__ kbf,
                                                  const unsigned short* __restrict__ vt,
                                                  const float* __restrict__ bias,
                                                  float* __restrict__ attn_out) {
  __shared__ alignas(16) unsigned short Qs[64 * 72];
  __shared__ alignas(16) unsigned short Ks[64 * 72];
  __shared__ alignas(16) unsigned short Vs[64 * 72];  // rows = d, cols = m
  __shared__ alignas(16) unsigned short Pt[4][64 * 20];  // per-wave: rows = m, cols = l
  const int t = threadIdx.x;
  const int lane = t & 63, w = t >> 6;
  const int c = lane & 15, q8 = lane >> 4;
  const int bh = blockIdx.y, qt = blockIdx.x;
  const unsigned short* qg = qbf + (size_t)bh * 65536 + qt * 4096;
  const unsigned short* kg = kbf + (size_t)bh * 65536;
  const unsigned short* vg = vt + (size_t)bh * 65536;
  const float* bg = bias + (size_t)bh * 1024;

  // stage Q (64x64 bf16)
#pragma unroll
  for (int s = 0; s < 2; ++s) {
    int idx = t + s * 256;
    int r = idx >> 3, c8 = (idx & 7) << 3;
    *(bf16x8*)&Qs[r * 72 + c8] = *(const bf16x8*)(qg + r * 64 + c8);
  }
  __syncthreads();
  bf16x8 aq0 = *(const bf16x8*)&Qs[(w * 16 + c) * 72 + q8 * 8];
  bf16x8 aq1 = *(const bf16x8*)&Qs[(w * 16 + c) * 72 + q8 * 8 + 32];

  float m_st[4], l_st[4];
  f32x4 o[4];
#pragma unroll
  for (int r = 0; r < 4; ++r) { m_st[r] = -INFINITY; l_st[r] = 0.0f; }
#pragma unroll
  for (int nt = 0; nt < 4; ++nt) o[nt] = (f32x4){0.f, 0.f, 0.f, 0.f};

  for (int kt = 0; kt < 16; ++kt) {
    __syncthreads();  // prior PV reads of Vs done before restage
#pragma unroll
    for (int s = 0; s < 2; ++s) {
      int idx = t + s * 256;
      int r = idx >> 3, c8 = (idx & 7) << 3;
      *(bf16x8*)&Ks[r * 72 + c8] = *(const bf16x8*)(kg + (kt * 64 + r) * 64 + c8);
      *(bf16x8*)&Vs[r * 72 + c8] = *(const bf16x8*)(vg + r * 1024 + kt * 64 + c8);
    }
    __syncthreads();
    // S = Q . K'^T  (C layout: col=lane&15=key, row=q8*4+reg=query)
    f32x4 sc[4];
#pragma unroll
    for (int nt = 0; nt < 4; ++nt) {
      bf16x8 bk0 = *(const bf16x8*)&Ks[(nt * 16 + c) * 72 + q8 * 8];
      bf16x8 bk1 = *(const bf16x8*)&Ks[(nt * 16 + c) * 72 + q8 * 8 + 32];
      f32x4 z = (f32x4){0.f, 0.f, 0.f, 0.f};
      z = __builtin_amdgcn_mfma_f32_16x16x32_bf16(aq0, bk0, z, 0, 0, 0);
      z = __builtin_amdgcn_mfma_f32_16x16x32_bf16(aq1, bk1, z, 0, 0, 0);
      sc[nt] = z;
    }
    float bb[4];
#pragma unroll
    for (int nt = 0; nt < 4; ++nt) bb[nt] = bg[kt * 64 + nt * 16 + c];
    // online softmax per row (reg r); reduce across 16 lanes of the row group
#pragma unroll
    for (int r = 0; r < 4; ++r) {
      float sv[4];
#pragma unroll
      for (int nt = 0; nt < 4; ++nt) sv[nt] = (sc[nt][r] + bb[nt]) * 0.125f;
      float mx = fmaxf(fmaxf(sv[0], sv[1]), fmaxf(sv[2], sv[3]));
#pragma unroll
      for (int msk = 1; msk < 16; msk <<= 1) mx = fmaxf(mx, __shfl_xor(mx, msk));
      float mn = fmaxf(m_st[r], mx);
      float al = __expf(m_st[r] - mn);
      m_st[r] = mn;
      float su = 0.0f;
#pragma unroll
      for (int nt = 0; nt < 4; ++nt) { sv[nt] = __expf(sv[nt] - mn); su += sv[nt]; }
#pragma unroll
      for (int msk = 1; msk < 16; msk <<= 1) su += __shfl_xor(su, msk);
      l_st[r] = l_st[r] * al + su;
#pragma unroll
      for (int nt = 0; nt < 4; ++nt) {
        o[nt][r] *= al;
        sc[nt][r] = sv[nt];
      }
    }
    // P -> per-wave LDS, transposed (Pt[m][l]); C-layout regs are 4 consecutive rows
#pragma unroll
    for (int nt = 0; nt < 4; ++nt) {
      ushort4 pk;
      pk.x = f2b(sc[nt][0]); pk.y = f2b(sc[nt][1]);
      pk.z = f2b(sc[nt][2]); pk.w = f2b(sc[nt][3]);
      *(ushort4*)&Pt[w][(nt * 16 + c) * 20 + q8 * 4] = pk;
    }
    // O += P @ V
#pragma unroll
    for (int s = 0; s < 2; ++s) {
      int mbase = 32 * s + 8 * q8;
      bf16x8 ap;
#pragma unroll
      for (int j = 0; j < 8; ++j) ap[j] = (short)Pt[w][(mbase + j) * 20 + c];
#pragma unroll
      for (int nt = 0; nt < 4; ++nt) {
        bf16x8 bv = *(const bf16x8*)&Vs[(nt * 16 + c) * 72 + mbase];
        o[nt] = __builtin_amdgcn_mfma_f32_16x16x32_bf16(ap, bv, o[nt], 0, 0, 0);
      }
    }
  }
  // epilogue
  const int bidx = bh >> 3, h = bh & 7;
#pragma unroll
  for (int r = 0; r < 4; ++r) {
    float inv = 1.0f / l_st[r];
    int l = qt * 64 + w * 16 + 4 * q8 + r;
    size_t base = (size_t)(bidx * 1024 + l) * 512 + h * 64;
#pragma unroll
    for (int nt = 0; nt < 4; ++nt) attn_out[base + nt * 16 + c] = o[nt][r] * inv;
  }
}

extern "C" void kernel_launch(void* const* d_in, const int* in_sizes, int n_in,
                              void* d_out, int out_size, void* d_ws, size_t ws_size,
                              hipStream_t stream) {
  const float* x      = (const float*)d_in[0];
  const float* gamma  = (const float*)d_in[1];
  const float* beta   = (const float*)d_in[2];
  const float* w_qkv  = (const float*)d_in[3];
  const float* b_qkv  = (const float*)d_in[4];
  const float* w_pos  = (const float*)d_in[5];
  const float* w_out  = (const float*)d_in[6];
  const float* b_out  = (const float*)d_in[7];
  const float* u_bias = (const float*)d_in[8];
  const float* v_bias = (const float*)d_in[9];
  float* out = (float*)d_out;
  float* ws = (float*)d_ws;

  // ws layout (floats):
  // region0 [0, 4M): xn -> pe -> {qbf16 [0,2M), kbf16 [2M,4M)}
  // qb f32 [4M, 8M); kb f32 [8M, 12M) -> vt bf16 [8M, 10M) after fold
  // vbuf f32 [12M, 16M) -> attn_out f32 after transv
  // posb [16M, 16.5M); biasb [16.5M, +64K)
  float* region0 = ws;
  float* qb    = ws + 4194304;
  float* kb    = ws + 8388608;
  float* vbuf  = ws + 12582912;
  float* posb  = ws + 16777216;
  float* biasb = ws + 17301504;
  unsigned short* qbf16 = (unsigned short*)ws;
  unsigned short* kbf16 = (unsigned short*)(ws + 2097152);
  unsigned short* vtb   = (unsigned short*)kb;
  float* attn = vbuf;

  ln_kernel<<<8192, 256, 0, stream>>>(x, gamma, beta, region0);
  gemm_nt<<<dim3(24, 128), dim3(16, 16), 0, stream>>>(region0, w_qkv, b_qkv, qb,
                                                      8192, 1536, 512, 0);
  pe_kernel<<<2048, 256, 0, stream>>>(region0);
  gemm_nt<<<dim3(8, 16), dim3(16, 16), 0, stream>>>(region0, w_pos, nullptr, posb,
                                                    1024, 512, 512, 1);
  fold_kernel<<<16384, 256, 0, stream>>>(kb, posb, u_bias, v_bias, biasb, kbf16);
  convq_kernel<<<4096, 256, 0, stream>>>(qb, qbf16);
  transv_kernel<<<dim3(16, 64), 256, 0, stream>>>(vbuf, vtb);
  flash_mfma<<<dim3(16, 64), 256, 0, stream>>>(qbf16, kbf16, vtb, biasb, attn);
  gemm_nt<<<dim3(8, 128), dim3(16, 16), 0, stream>>>(attn, w_out, b_out, out,
                                                     8192, 512, 512, 2);
}

// Round 3
// 250.704 us; speedup vs baseline: 3.3616x; 2.2029x over previous
//
#include <hip/hip_runtime.h>
#include <math.h>

static constexpr int Bn = 8, Ln = 1024, Dm = 512, Hn = 8, DhN = 64;

typedef short bf16x8 __attribute__((ext_vector_type(8)));
typedef float f32x4 __attribute__((ext_vector_type(4)));

static __device__ __forceinline__ unsigned short f2b(float f) {
  union { float f; unsigned int u; } x;
  x.f = f;
  unsigned int u = x.u;
  unsigned int r = (u + 0x7FFFu + ((u >> 16) & 1u)) >> 16;  // RNE
  return (unsigned short)r;
}
static __device__ __forceinline__ float b2f(unsigned short u) {
  union { unsigned int u; float f; } x;
  x.u = ((unsigned int)u) << 16;
  return x.f;
}

#define GLDS16(g, l)                                                        \
  __builtin_amdgcn_global_load_lds((const __attribute__((address_space(1))) void*)(g), \
                                   (__attribute__((address_space(3))) void*)(l), 16, 0, 0)

// ---------------- LayerNorm -> bf16 ----------------
__global__ __launch_bounds__(256) void ln_kernel(const float* __restrict__ x,
                                                 const float* __restrict__ gamma,
                                                 const float* __restrict__ beta,
                                                 unsigned short* __restrict__ xn) {
  int row = blockIdx.x;
  int t = threadIdx.x;
  const float2 v = *(const float2*)(x + (size_t)row * Dm + t * 2);
  float s = v.x + v.y;
  float sq = v.x * v.x + v.y * v.y;
#pragma unroll
  for (int off = 32; off > 0; off >>= 1) {
    s += __shfl_down(s, off);
    sq += __shfl_down(sq, off);
  }
  __shared__ float red[8];
  int wave = t >> 6, lane = t & 63;
  if (lane == 0) { red[wave * 2] = s; red[wave * 2 + 1] = sq; }
  __syncthreads();
  float S = red[0] + red[2] + red[4] + red[6];
  float SQ = red[1] + red[3] + red[5] + red[7];
  float mu = S * (1.0f / Dm);
  float var = SQ * (1.0f / Dm) - mu * mu;
  float rstd = rsqrtf(var + 1e-5f);
  int c = t * 2;
  ushort2 o;
  o.x = f2b((v.x - mu) * rstd * gamma[c] + beta[c]);
  o.y = f2b((v.y - mu) * rstd * gamma[c + 1] + beta[c + 1]);
  *(ushort2*)(xn + (size_t)row * Dm + c) = o;
}

// ---------------- Sinusoidal pe[l][k] -> bf16 ----------------
__global__ __launch_bounds__(256) void pe_kernel(unsigned short* __restrict__ pe) {
  int idx = blockIdx.x * 256 + threadIdx.x;
  int l = idx >> 9, k = idx & 511;
  float freq = expf(-0.0359778921f * (float)k);
  float angle = (float)(l - k) * freq;
  pe[idx] = f2b((k & 1) ? sinf(angle) : cosf(angle));
}

// ---------------- f32 -> bf16 weight conversion ----------------
__global__ __launch_bounds__(256) void conv_kernel(const float* __restrict__ a,
                                                   unsigned short* __restrict__ b) {
  int i = blockIdx.x * 256 + threadIdx.x;
  float4 v = *(const float4*)(a + (size_t)i * 4);
  ushort4 o;
  o.x = f2b(v.x); o.y = f2b(v.y); o.z = f2b(v.z); o.w = f2b(v.w);
  *(ushort4*)(b + (size_t)i * 4) = o;
}

// ---------------- bf16 MFMA NT GEMM: C[m][n] = sum_k A[m][k]*Bw[n][k] (+bias[n]) ----------------
// 128x128 tile, BK=64, 4 waves (2x2 of 64x64), global_load_lds staging, XOR-swizzled LDS.
// mode 0: scatter to q/k/v bf16 (B,H,L,Dh); mode 1: posb f32 (H,L,Dh); mode 2: outf f32 row-major.
__global__ __launch_bounds__(256) void gemm_mfma(const unsigned short* __restrict__ A,
                                                 const unsigned short* __restrict__ Bw,
                                                 const float* __restrict__ bias,
                                                 float* __restrict__ outf,
                                                 unsigned short* __restrict__ oq,
                                                 unsigned short* __restrict__ ok,
                                                 unsigned short* __restrict__ ov,
                                                 int M, int N, int K, int mode) {
  __shared__ alignas(16) unsigned short As[128 * 64];
  __shared__ alignas(16) unsigned short Bs[128 * 64];
  const int t = threadIdx.x;
  const int lane = t & 63, w = t >> 6;
  const int c = lane & 15, q8 = lane >> 4;
  const int wm = (w & 1) * 64, wn = (w >> 1) * 64;
  const int m0 = blockIdx.y * 128, n0 = blockIdx.x * 128;

  f32x4 acc[4][4];
#pragma unroll
  for (int i = 0; i < 4; ++i)
#pragma unroll
    for (int j = 0; j < 4; ++j) acc[i][j] = (f32x4){0.f, 0.f, 0.f, 0.f};

  // staging geometry: granule g = (w*4+j)*64 + lane holds (row=g>>3, colgran=(g&7)^(row&7))
  const int srow = lane >> 3;                    // also = row&7 for every inst
  const int scol = ((lane & 7) ^ srow) * 8;      // swizzled source column (ushorts)
  int arow[4];
#pragma unroll
  for (int j = 0; j < 4; ++j) arow[j] = w * 32 + j * 8 + srow;

  for (int k0 = 0; k0 < K; k0 += 64) {
    __syncthreads();
#pragma unroll
    for (int j = 0; j < 4; ++j) {
      GLDS16(A + (size_t)(m0 + arow[j]) * K + k0 + scol,
             As + ((w * 4 + j) * 64 + lane) * 8);
      GLDS16(Bw + (size_t)(n0 + arow[j]) * K + k0 + scol,
             Bs + ((w * 4 + j) * 64 + lane) * 8);
    }
    __syncthreads();
#pragma unroll
    for (int kk = 0; kk < 2; ++kk) {
      bf16x8 a[4], b[4];
      const int q = kk * 4 + q8;
#pragma unroll
      for (int i = 0; i < 4; ++i) {
        int r = wm + i * 16 + c;
        a[i] = *(const bf16x8*)&As[r * 64 + ((q ^ (r & 7)) * 8)];
      }
#pragma unroll
      for (int j = 0; j < 4; ++j) {
        int r = wn + j * 16 + c;
        b[j] = *(const bf16x8*)&Bs[r * 64 + ((q ^ (r & 7)) * 8)];
      }
#pragma unroll
      for (int i = 0; i < 4; ++i)
#pragma unroll
        for (int j = 0; j < 4; ++j)
          acc[i][j] = __builtin_amdgcn_mfma_f32_16x16x32_bf16(a[i], b[j], acc[i][j], 0, 0, 0);
    }
  }
  // epilogue: C layout col=lane&15, row=(lane>>4)*4+reg
#pragma unroll
  for (int i = 0; i < 4; ++i) {
#pragma unroll
    for (int r = 0; r < 4; ++r) {
      int m = m0 + wm + i * 16 + q8 * 4 + r;
#pragma unroll
      for (int j = 0; j < 4; ++j) {
        int n = n0 + wn + j * 16 + c;
        float val = acc[i][j][r] + (bias ? bias[n] : 0.0f);
        if (mode == 0) {
          int part = n >> 9, h = (n >> 6) & 7, dh = n & 63;
          int bb = m >> 10, l = m & 1023;
          size_t idx = (size_t)((bb * 8 + h) * 1024 + l) * 64 + dh;
          unsigned short* dst = (part == 0) ? oq : (part == 1) ? ok : ov;
          dst[idx] = f2b(val);
        } else if (mode == 1) {
          int h = n >> 6, dh = n & 63;
          outf[(size_t)(h * 1024 + m) * 64 + dh] = val;
        } else {
          outf[(size_t)m * N + n] = val;
        }
      }
    }
  }
}

// ---------------- Fold (in place): K' = k + pos[h] (bf16); bias = u.k + vb.pos ----------------
__global__ __launch_bounds__(256) void fold_kernel(unsigned short* __restrict__ kbuf,
                                                   const float* __restrict__ pos,
                                                   const float* __restrict__ ub,
                                                   const float* __restrict__ vbb,
                                                   float* __restrict__ biasout) {
  int t = threadIdx.x;
  int wave = t >> 6, lane = t & 63;
  int g = blockIdx.x * 4 + wave;  // [0, B*H*L)
  int h = (g >> 10) & 7;
  int m = g & 1023;
  float kv = b2f(kbuf[(size_t)g * 64 + lane]);
  float pv = pos[(size_t)(h * 1024 + m) * 64 + lane];
  float val = ub[h * 64 + lane] * kv + vbb[h * 64 + lane] * pv;
#pragma unroll
  for (int off = 32; off > 0; off >>= 1) val += __shfl_down(val, off);
  if (lane == 0) biasout[g] = val;
  kbuf[(size_t)g * 64 + lane] = f2b(kv + pv);
}

// ---------------- V bf16 (b,h,l,d) -> Vt bf16 (b,h,d,l) ----------------
__global__ __launch_bounds__(256) void transv_kernel(const unsigned short* __restrict__ v,
                                                     unsigned short* __restrict__ vt) {
  __shared__ unsigned short Ts[64 * 68];
  int t = threadIdx.x;
  int bh = blockIdx.y, lt = blockIdx.x;
  const unsigned short* vg = v + (size_t)bh * 65536 + lt * 4096;
#pragma unroll
  for (int s = 0; s < 4; ++s) {
    int idx = t + s * 256;
    int r = idx >> 4, c4 = (idx & 15) << 2;
    *(ushort4*)&Ts[r * 68 + c4] = *(const ushort4*)(vg + r * 64 + c4);
  }
  __syncthreads();
#pragma unroll
  for (int s = 0; s < 4; ++s) {
    int idx = t + s * 256;
    int d = idx >> 4, l4 = (idx & 15) << 2;
    ushort4 o;
    o.x = Ts[(l4 + 0) * 68 + d];
    o.y = Ts[(l4 + 1) * 68 + d];
    o.z = Ts[(l4 + 2) * 68 + d];
    o.w = Ts[(l4 + 3) * 68 + d];
    *(ushort4*)(vt + (size_t)bh * 65536 + d * 1024 + lt * 64 + l4) = o;
  }
}

// ---------------- Flash attention, bf16 MFMA; attn out bf16 ----------------
__global__ __launch_bounds__(256) void flash_mfma(const unsigned short* __restrict__ qbf,
                                                  const unsigned short* __restrict__ kbf,
                                                  const unsigned short* __restrict__ vt,
                                                  const float* __restrict__ bias,
                                                  unsigned short* __restrict__ attn_out) {
  __shared__ alignas(16) unsigned short Qs[64 * 72];
  __shared__ alignas(16) unsigned short Ks[64 * 72];
  __shared__ alignas(16) unsigned short Vs[64 * 72];
  __shared__ alignas(16) unsigned short Pt[4][64 * 20];
  const int t = threadIdx.x;
  const int lane = t & 63, w = t >> 6;
  const int c = lane & 15, q8 = lane >> 4;
  const int bh = blockIdx.y, qt = blockIdx.x;
  const unsigned short* qg = qbf + (size_t)bh * 65536 + qt * 4096;
  const unsigned short* kg = kbf + (size_t)bh * 65536;
  const unsigned short* vg = vt + (size_t)bh * 65536;
  const float* bg = bias + (size_t)bh * 1024;

#pragma unroll
  for (int s = 0; s < 2; ++s) {
    int idx = t + s * 256;
    int r = idx >> 3, c8 = (idx & 7) << 3;
    *(bf16x8*)&Qs[r * 72 + c8] = *(const bf16x8*)(qg + r * 64 + c8);
  }
  __syncthreads();
  bf16x8 aq0 = *(const bf16x8*)&Qs[(w * 16 + c) * 72 + q8 * 8];
  bf16x8 aq1 = *(const bf16x8*)&Qs[(w * 16 + c) * 72 + q8 * 8 + 32];

  float m_st[4], l_st[4];
  f32x4 o[4];
#pragma unroll
  for (int r = 0; r < 4; ++r) { m_st[r] = -INFINITY; l_st[r] = 0.0f; }
#pragma unroll
  for (int nt = 0; nt < 4; ++nt) o[nt] = (f32x4){0.f, 0.f, 0.f, 0.f};

  for (int kt = 0; kt < 16; ++kt) {
    __syncthreads();
#pragma unroll
    for (int s = 0; s < 2; ++s) {
      int idx = t + s * 256;
      int r = idx >> 3, c8 = (idx & 7) << 3;
      *(bf16x8*)&Ks[r * 72 + c8] = *(const bf16x8*)(kg + (kt * 64 + r) * 64 + c8);
      *(bf16x8*)&Vs[r * 72 + c8] = *(const bf16x8*)(vg + r * 1024 + kt * 64 + c8);
    }
    __syncthreads();
    f32x4 sc[4];
#pragma unroll
    for (int nt = 0; nt < 4; ++nt) {
      bf16x8 bk0 = *(const bf16x8*)&Ks[(nt * 16 + c) * 72 + q8 * 8];
      bf16x8 bk1 = *(const bf16x8*)&Ks[(nt * 16 + c) * 72 + q8 * 8 + 32];
      f32x4 z = (f32x4){0.f, 0.f, 0.f, 0.f};
      z = __builtin_amdgcn_mfma_f32_16x16x32_bf16(aq0, bk0, z, 0, 0, 0);
      z = __builtin_amdgcn_mfma_f32_16x16x32_bf16(aq1, bk1, z, 0, 0, 0);
      sc[nt] = z;
    }
    float bb[4];
#pragma unroll
    for (int nt = 0; nt < 4; ++nt) bb[nt] = bg[kt * 64 + nt * 16 + c];
#pragma unroll
    for (int r = 0; r < 4; ++r) {
      float sv[4];
#pragma unroll
      for (int nt = 0; nt < 4; ++nt) sv[nt] = (sc[nt][r] + bb[nt]) * 0.125f;
      float mx = fmaxf(fmaxf(sv[0], sv[1]), fmaxf(sv[2], sv[3]));
#pragma unroll
      for (int msk = 1; msk < 16; msk <<= 1) mx = fmaxf(mx, __shfl_xor(mx, msk));
      float mn = fmaxf(m_st[r], mx);
      float al = __expf(m_st[r] - mn);
      m_st[r] = mn;
      float su = 0.0f;
#pragma unroll
      for (int nt = 0; nt < 4; ++nt) { sv[nt] = __expf(sv[nt] - mn); su += sv[nt]; }
#pragma unroll
      for (int msk = 1; msk < 16; msk <<= 1) su += __shfl_xor(su, msk);
      l_st[r] = l_st[r] * al + su;
#pragma unroll
      for (int nt = 0; nt < 4; ++nt) {
        o[nt][r] *= al;
        sc[nt][r] = sv[nt];
      }
    }
#pragma unroll
    for (int nt = 0; nt < 4; ++nt) {
      ushort4 pk;
      pk.x = f2b(sc[nt][0]); pk.y = f2b(sc[nt][1]);
      pk.z = f2b(sc[nt][2]); pk.w = f2b(sc[nt][3]);
      *(ushort4*)&Pt[w][(nt * 16 + c) * 20 + q8 * 4] = pk;
    }
#pragma unroll
    for (int s = 0; s < 2; ++s) {
      int mbase = 32 * s + 8 * q8;
      bf16x8 ap;
#pragma unroll
      for (int j = 0; j < 8; ++j) ap[j] = (short)Pt[w][(mbase + j) * 20 + c];
#pragma unroll
      for (int nt = 0; nt < 4; ++nt) {
        bf16x8 bv = *(const bf16x8*)&Vs[(nt * 16 + c) * 72 + mbase];
        o[nt] = __builtin_amdgcn_mfma_f32_16x16x32_bf16(ap, bv, o[nt], 0, 0, 0);
      }
    }
  }
  const int bidx = bh >> 3, h = bh & 7;
#pragma unroll
  for (int r = 0; r < 4; ++r) {
    float inv = 1.0f / l_st[r];
    int l = qt * 64 + w * 16 + 4 * q8 + r;
    size_t base = (size_t)(bidx * 1024 + l) * 512 + h * 64;
#pragma unroll
    for (int nt = 0; nt < 4; ++nt) attn_out[base + nt * 16 + c] = f2b(o[nt][r] * inv);
  }
}

extern "C" void kernel_launch(void* const* d_in, const int* in_sizes, int n_in,
                              void* d_out, int out_size, void* d_ws, size_t ws_size,
                              hipStream_t stream) {
  const float* x      = (const float*)d_in[0];
  const float* gamma  = (const float*)d_in[1];
  const float* beta   = (const float*)d_in[2];
  const float* w_qkv  = (const float*)d_in[3];
  const float* b_qkv  = (const float*)d_in[4];
  const float* w_pos  = (const float*)d_in[5];
  const float* w_out  = (const float*)d_in[6];
  const float* b_out  = (const float*)d_in[7];
  const float* u_bias = (const float*)d_in[8];
  const float* v_bias = (const float*)d_in[9];
  float* out = (float*)d_out;

  unsigned short* wsu = (unsigned short*)d_ws;
  unsigned short* xnb   = wsu;                    // 4M ushort
  unsigned short* peb   = wsu + 4194304;          // 512K
  unsigned short* wqkvb = wsu + 4718592;          // 768K
  unsigned short* wposb = wsu + 5505024;          // 256K
  unsigned short* woutb = wsu + 5767168;          // 256K
  unsigned short* qbf   = wsu + 6291456;          // 4M
  unsigned short* kbf   = wsu + 10485760;         // 4M (K' after fold)
  unsigned short* vbf   = wsu + 14680064;         // 4M
  unsigned short* vtb   = wsu + 18874368;         // 4M
  unsigned short* attnb = wsu + 23068672;         // 4M
  float* posb  = (float*)(wsu + 27262976);        // 512K floats
  float* biasb = (float*)(wsu + 28311552);        // 64K floats

  ln_kernel<<<8192, 256, 0, stream>>>(x, gamma, beta, xnb);
  pe_kernel<<<2048, 256, 0, stream>>>(peb);
  conv_kernel<<<768, 256, 0, stream>>>(w_qkv, wqkvb);
  conv_kernel<<<256, 256, 0, stream>>>(w_pos, wposb);
  conv_kernel<<<256, 256, 0, stream>>>(w_out, woutb);
  gemm_mfma<<<dim3(12, 64), 256, 0, stream>>>(xnb, wqkvb, b_qkv, nullptr, qbf, kbf, vbf,
                                              8192, 1536, 512, 0);
  gemm_mfma<<<dim3(4, 8), 256, 0, stream>>>(peb, wposb, nullptr, posb, nullptr, nullptr, nullptr,
                                            1024, 512, 512, 1);
  fold_kernel<<<16384, 256, 0, stream>>>(kbf, posb, u_bias, v_bias, biasb);
  transv_kernel<<<dim3(16, 64), 256, 0, stream>>>(vbf, vtb);
  flash_mfma<<<dim3(16, 64), 256, 0, stream>>>(qbf, kbf, vtb, biasb, attnb);
  gemm_mfma<<<dim3(4, 64), 256, 0, stream>>>(attnb, woutb, b_out, out, nullptr, nullptr, nullptr,
                                             8192, 512, 512, 2);
}